// Round 8
// baseline (181.365 us; speedup 1.0000x reference)
//
#include <hip/hip_runtime.h>
#include <cstdint>
#include <cstddef>

// Problem constants
constexpr int N = 4096;
constexpr int B = 32;
constexpr int BN = B * N;             // 131072
constexpr size_t NN = (size_t)N * N;  // 16777216

// Two-family GEMM pass (1024 blocks total = 4/CU):
//  Family A (gemm1 + W_out): 512 blocks = (it 0..31) x (jc 0..15)
//     i-panel 128 rows, j-chunk 256 (2 subtiles of 128). K accum = 256.
//  Family B (gemm0):         512 blocks = (jt 0..31) x (ic 0..15)
//     j-panel 128 cols, i-chunk 256 (4 subtiles of 64).  K accum = 256.
constexpr int ABLK = 512;
constexpr int BBLK = 512;
constexpr int NPSWT = 16;             // partSWT copies (jc)
constexpr int NPSW = 16;              // partSW copies (ic)
constexpr int LDTB = 136;             // family B tile row stride (bf16 elems)

constexpr float ALPHA = 0.025f;
constexpr float BETA = 0.00025f;
constexpr float T_NOW = 10.0f;
constexpr float INV_EXP_TAU = 0.02f;          // 1/50
constexpr float INV_TAU_V = 0.98019867f;      // exp(-1/50)
constexpr float INV_TAU_I = 0.36787944f;      // exp(-1)

typedef __attribute__((ext_vector_type(8))) short short8;
typedef __attribute__((ext_vector_type(4))) float f32x4;

__device__ inline unsigned short f2bf(float f) {
  uint32_t u = __float_as_uint(f);
  u += 0x7FFFu + ((u >> 16) & 1u);   // RNE
  return (unsigned short)(u >> 16);
}

// W-update recomputed on the fly:
//   u = clip(w + BETA - fac_row * exp(|mst_row - mst_col|/50), 0, 1); keep w where w<=0
__device__ inline float wupd(float w, float mrow, float frow, float mcol) {
  float d = fabsf(mrow - mcol);
  float u = w + BETA - frow * __expf(d * INV_EXP_TAU);
  u = fminf(fmaxf(u, 0.0f), 1.0f);
  return (w > 0.0f) ? u : w;
}

// Barrier with LDS-only ordering: does NOT drain vmcnt, so global stores
// (W_out) and prefetch loads stay in flight across phases. The compiler
// still inserts vmcnt waits before any load result is USED.
__device__ inline void bar_lgkm() {
  asm volatile("s_waitcnt lgkmcnt(0)" ::: "memory");
  __builtin_amdgcn_sched_barrier(0);
  __builtin_amdgcn_s_barrier();
}

// ---------------------------------------------------------------------------
// Pass A: per-neuron spike masks + max_st + rowfac; writes S (f32) and S_bf.
// ---------------------------------------------------------------------------
__global__ __launch_bounds__(256) void pass_a(
    const float* __restrict__ mem_pot, const float* __restrict__ mem_pot_p,
    const float* __restrict__ st, float* __restrict__ S_out,
    unsigned short* __restrict__ S_bf,
    uint32_t* __restrict__ maskS, uint32_t* __restrict__ maskSP,
    float* __restrict__ max_st, float* __restrict__ rowfac) {
  int j = blockIdx.x * blockDim.x + threadIdx.x;
  if (j >= N) return;
  float stj = st[j];
  uint32_t ms = 0u, msp = 0u;
  float maxv = -3.0e38f;
  #pragma unroll
  for (int b = 0; b < B; ++b) {
    float p = mem_pot[b * N + j];
    float pp = mem_pot_p[b * N + j];
    bool s = (p - 1.0f) > 0.0f;
    bool sp = ((pp - 1.0f) - ALPHA) > 0.0f;
    S_out[b * N + j] = s ? 1.0f : 0.0f;
    S_bf[b * N + j] = s ? 0x3F80u : 0u;   // bf16 1.0 / 0.0
    ms |= (uint32_t)s << b;
    msp |= (uint32_t)sp << b;
    maxv = fmaxf(maxv, s ? T_NOW : stj);
  }
  maskS[j] = ms;
  maskSP[j] = msp;
  max_st[j] = maxv;
  rowfac[j] = msp ? ALPHA : 0.0f;
}

// ---------------------------------------------------------------------------
// Two-family GEMM pass (one launch; block-uniform branch).
// MFMA layouts (verified rounds 0-7): A[m=lane&15][k=quad*8+e],
// B[k=quad*8+e][n=lane&15], C/D: col=lane&15, row=quad*4+reg.
// Family A LDS tile uses 16B-unit XOR swizzle: unit' = unit ^ (row&7).
// ---------------------------------------------------------------------------
__global__ __launch_bounds__(256, 4) void pass_gemms(
    const float* __restrict__ W, const unsigned short* __restrict__ S_bf,
    const float* __restrict__ max_st, const float* __restrict__ rowfac,
    float* __restrict__ Wout, float* __restrict__ partSW,
    float* __restrict__ partSWT) {
  __shared__ __align__(16) char smem[33792];

  int tid = threadIdx.x;
  int wv = tid >> 6;
  int lane = tid & 63;
  int quad = lane >> 4;
  int nl = lane & 15;
  int row8 = tid >> 5;               // 0..7 (stage-phase row stripe)
  int c4 = tid & 31;                 // float4 column 0..31

  if (blockIdx.x < ABLK) {
    // =================== Family A: gemm1 (SWT) + W_out ===================
    int it = blockIdx.x & 31;
    int jc = blockIdx.x >> 5;        // 0..15
    int i0 = it * 128;
    float* mstIA = (float*)(smem + 32768);
    float* facIA = mstIA + 128;

    if (tid < 128) {
      mstIA[tid] = max_st[i0 + tid];
      facIA[tid] = rowfac[i0 + tid];
    }

    // prefetch subtile 0 FIRST-half rows (0..63): stays in flight over barrier
    float4 pfA[8];
    {
      const float* wb = W + (size_t)(i0 + row8) * N + jc * 256 + c4 * 4;
      #pragma unroll
      for (int p = 0; p < 8; ++p)
        pfA[p] = *(const float4*)(wb + (size_t)(p * 8) * N);
    }

    f32x4 acc[2][2];                 // [ntile][batch-half]
    #pragma unroll
    for (int a = 0; a < 2; ++a)
      #pragma unroll
      for (int h = 0; h < 2; ++h) acc[a][h] = (f32x4){0.f, 0.f, 0.f, 0.f};

    bar_lgkm();                      // mstIA/facIA visible

    #pragma unroll 1
    for (int jsub = 0; jsub < 2; ++jsub) {
      int jb = jc * 256 + jsub * 128;
      // second-half rows (64..127) of this subtile
      float4 pfB2[8];
      {
        const float* wb = W + (size_t)(i0 + 64 + row8) * N + jb + c4 * 4;
        #pragma unroll
        for (int p = 0; p < 8; ++p)
          pfB2[p] = *(const float4*)(wb + (size_t)(p * 8) * N);
      }
      // A-fragments for this j-window (used after the barrier)
      short8 aA0[4], aA1[4];
      #pragma unroll
      for (int ks = 0; ks < 4; ++ks) {
        int kg = jb + ks * 32 + quad * 8;
        aA0[ks] = *(const short8*)(S_bf + (size_t)nl * N + kg);
        aA1[ks] = *(const short8*)(S_bf + (size_t)(nl + 16) * N + kg);
      }
      float4 mj4 = *(const float4*)(max_st + jb + c4 * 4);

      // stage rows 0..63 (pfA), then 64..127 (pfB2)
      #pragma unroll
      for (int p = 0; p < 8; ++p) {
        int r = p * 8 + row8;
        float mi = mstIA[r];
        float fi = facIA[r];
        f32x4 u;
        u[0] = wupd(pfA[p].x, mi, fi, mj4.x);
        u[1] = wupd(pfA[p].y, mi, fi, mj4.y);
        u[2] = wupd(pfA[p].z, mi, fi, mj4.z);
        u[3] = wupd(pfA[p].w, mi, fi, mj4.w);
        __builtin_nontemporal_store(
            u, (f32x4*)(Wout + (size_t)(i0 + r) * N + jb + c4 * 4));
        uint32_t d0 = (uint32_t)f2bf(u[0]) | ((uint32_t)f2bf(u[1]) << 16);
        uint32_t d1 = (uint32_t)f2bf(u[2]) | ((uint32_t)f2bf(u[3]) << 16);
        uint2 dd; dd.x = d0; dd.y = d1;
        *(uint2*)(smem + r * 256 + ((((c4 >> 1) ^ (r & 7))) << 4) +
                  ((c4 & 1) << 3)) = dd;
      }
      #pragma unroll
      for (int p = 0; p < 8; ++p) {
        int r = 64 + p * 8 + row8;
        float mi = mstIA[r];
        float fi = facIA[r];
        f32x4 u;
        u[0] = wupd(pfB2[p].x, mi, fi, mj4.x);
        u[1] = wupd(pfB2[p].y, mi, fi, mj4.y);
        u[2] = wupd(pfB2[p].z, mi, fi, mj4.z);
        u[3] = wupd(pfB2[p].w, mi, fi, mj4.w);
        __builtin_nontemporal_store(
            u, (f32x4*)(Wout + (size_t)(i0 + r) * N + jb + c4 * 4));
        uint32_t d0 = (uint32_t)f2bf(u[0]) | ((uint32_t)f2bf(u[1]) << 16);
        uint32_t d1 = (uint32_t)f2bf(u[2]) | ((uint32_t)f2bf(u[3]) << 16);
        uint2 dd; dd.x = d0; dd.y = d1;
        *(uint2*)(smem + r * 256 + ((((c4 >> 1) ^ (r & 7))) << 4) +
                  ((c4 & 1) << 3)) = dd;
      }
      // prefetch next subtile's first half (in flight through MFMA phase)
      if (jsub == 0) {
        const float* wb =
            W + (size_t)(i0 + row8) * N + jc * 256 + 128 + c4 * 4;
        #pragma unroll
        for (int p = 0; p < 8; ++p)
          pfA[p] = *(const float4*)(wb + (size_t)(p * 8) * N);
      }
      bar_lgkm();                    // tile ready (vmcnt NOT drained)

      // gemm1 MFMA: wave owns rows wv*32..wv*32+31 (2 n-tiles of 16 i's)
      #pragma unroll
      for (int ks = 0; ks < 4; ++ks) {
        #pragma unroll
        for (int nt = 0; nt < 2; ++nt) {
          int rr = wv * 32 + nt * 16 + nl;       // tile row (= i local)
          short8 bfr = *(const short8*)(
              smem + rr * 256 + ((((ks * 4 + quad) ^ (rr & 7))) << 4));
          acc[nt][0] =
              __builtin_amdgcn_mfma_f32_16x16x32_bf16(aA0[ks], bfr, acc[nt][0], 0, 0, 0);
          acc[nt][1] =
              __builtin_amdgcn_mfma_f32_16x16x32_bf16(aA1[ks], bfr, acc[nt][1], 0, 0, 0);
        }
      }
      if (jsub == 0) bar_lgkm();     // reads done before overwrite
    }

    // epilogue: one partSWT store (K=256 accumulated)
    size_t baseA = (size_t)jc * BN;
    #pragma unroll
    for (int nt = 0; nt < 2; ++nt) {
      int ig = i0 + wv * 32 + nt * 16 + nl;
      #pragma unroll
      for (int r = 0; r < 4; ++r) {
        partSWT[baseA + (size_t)(quad * 4 + r) * N + ig] = acc[nt][0][r];
        partSWT[baseA + (size_t)(16 + quad * 4 + r) * N + ig] = acc[nt][1][r];
      }
    }
  } else {
    // =================== Family B: gemm0 (SW) ===================
    int idx = blockIdx.x - ABLK;
    int jt = idx & 31;
    int ic = idx >> 5;               // 0..15
    int j0 = jt * 128;
    int ibase = ic * 256;
    unsigned short* tileB = (unsigned short*)smem;      // [64][LDTB]
    float* mstIB = (float*)(smem + 17408);
    float* facIB = mstIB + 256;
    float* mstJB = facIB + 256;

    mstIB[tid] = max_st[ibase + tid];
    facIB[tid] = rowfac[ibase + tid];
    if (tid < 128) mstJB[tid] = max_st[j0 + tid];

    float4 pf[8];
    {
      const float* wb = W + (size_t)(ibase + row8) * N + j0 + c4 * 4;
      #pragma unroll
      for (int p = 0; p < 8; ++p)
        pf[p] = *(const float4*)(wb + (size_t)(p * 8) * N);
    }

    f32x4 accB[2][2];                // [j-ntile][batch-half]
    #pragma unroll
    for (int a = 0; a < 2; ++a)
      #pragma unroll
      for (int h = 0; h < 2; ++h) accB[a][h] = (f32x4){0.f, 0.f, 0.f, 0.f};

    bar_lgkm();                      // mst/fac visible

    #pragma unroll 1
    for (int isub = 0; isub < 4; ++isub) {
      // A-fragments for this i-window (complete during stage)
      short8 aB0[2], aB1[2];
      #pragma unroll
      for (int ks = 0; ks < 2; ++ks) {
        int kg = ibase + isub * 64 + ks * 32 + quad * 8;
        aB0[ks] = *(const short8*)(S_bf + (size_t)nl * N + kg);
        aB1[ks] = *(const short8*)(S_bf + (size_t)(nl + 16) * N + kg);
      }
      float4 mjB = *(const float4*)(mstJB + c4 * 4);
      #pragma unroll
      for (int p = 0; p < 8; ++p) {
        int r = p * 8 + row8;
        float mi = mstIB[isub * 64 + r];
        float fi = facIB[isub * 64 + r];
        float ux = wupd(pf[p].x, mi, fi, mjB.x);
        float uy = wupd(pf[p].y, mi, fi, mjB.y);
        float uz = wupd(pf[p].z, mi, fi, mjB.z);
        float uw = wupd(pf[p].w, mi, fi, mjB.w);
        uint32_t d0 = (uint32_t)f2bf(ux) | ((uint32_t)f2bf(uy) << 16);
        uint32_t d1 = (uint32_t)f2bf(uz) | ((uint32_t)f2bf(uw) << 16);
        uint2 dd; dd.x = d0; dd.y = d1;
        *(uint2*)((char*)tileB + r * (LDTB * 2) + c4 * 8) = dd;
      }
      // prefetch next sub-tile (in flight through MFMA phase)
      if (isub + 1 < 4) {
        const float* wb =
            W + (size_t)(ibase + (isub + 1) * 64 + row8) * N + j0 + c4 * 4;
        #pragma unroll
        for (int p = 0; p < 8; ++p)
          pf[p] = *(const float4*)(wb + (size_t)(p * 8) * N);
      }
      bar_lgkm();                    // tile ready (vmcnt NOT drained)

      // gemm0 MFMA: wave owns j-ntiles wv*2, wv*2+1 (balanced)
      #pragma unroll
      for (int ks = 0; ks < 2; ++ks) {
        #pragma unroll
        for (int t = 0; t < 2; ++t) {
          int js = wv * 2 + t;
          short8 b;
          #pragma unroll
          for (int e = 0; e < 8; ++e)
            b[e] = (short)tileB[(ks * 32 + quad * 8 + e) * LDTB + js * 16 + nl];
          accB[t][0] =
              __builtin_amdgcn_mfma_f32_16x16x32_bf16(aB0[ks], b, accB[t][0], 0, 0, 0);
          accB[t][1] =
              __builtin_amdgcn_mfma_f32_16x16x32_bf16(aB1[ks], b, accB[t][1], 0, 0, 0);
        }
      }
      if (isub + 1 < 4) bar_lgkm();  // reads done before overwrite
    }

    // epilogue: one partSW store (K=256 accumulated)
    size_t baseB = (size_t)ic * BN;
    #pragma unroll
    for (int t = 0; t < 2; ++t) {
      int jg = j0 + (wv * 2 + t) * 16 + nl;
      #pragma unroll
      for (int r = 0; r < 4; ++r) {
        partSW[baseB + (size_t)(quad * 4 + r) * N + jg] = accB[t][0][r];
        partSW[baseB + (size_t)(16 + quad * 4 + r) * N + jg] = accB[t][1][r];
      }
    }
  }
}

// ---------------------------------------------------------------------------
// Pass D: reduce partials, integrate + leak + reset + refractory.
// ---------------------------------------------------------------------------
__global__ __launch_bounds__(256) void pass_d(
    const float* __restrict__ inp, const float* __restrict__ mem_pot,
    const float* __restrict__ mem_cur, const float* __restrict__ mem_pot_p,
    const float* __restrict__ mem_cur_p, const int* __restrict__ refrac_in,
    const uint32_t* __restrict__ maskS, const uint32_t* __restrict__ maskSP,
    const float* __restrict__ partSW, const float* __restrict__ partSWT,
    float* __restrict__ pot_out, float* __restrict__ cur_out,
    float* __restrict__ potp_out, float* __restrict__ curp_out,
    float* __restrict__ refrac_out) {
  int e = blockIdx.x * 256 + threadIdx.x;
  int b = e >> 12;
  int j = e & (N - 1);

  float SW = 0.0f, SWT = 0.0f;
  #pragma unroll
  for (int c = 0; c < NPSW; ++c) SW += partSW[(size_t)c * BN + e];
  #pragma unroll
  for (int c = 0; c < NPSWT; ++c) SWT += partSWT[(size_t)c * BN + e];

  int r = refrac_in[e];
  int rd = (r > 0) ? (r - 1) : r;
  bool active = (rd == 0);
  bool s = (maskS[j] >> b) & 1u;
  bool sp = (maskSP[j] >> b) & 1u;
  float cur = mem_cur[e], pot = mem_pot[e];
  float curp = mem_cur_p[e], potp = mem_pot_p[e];

  float cur_n = active ? (inp[e] + SW + cur) : cur;
  float curp_n = active ? (SWT + curp) : curp;
  float pot_n = active ? (cur_n + pot) : pot;
  float potp_n = active ? (curp_n + potp) : potp;

  pot_n *= INV_TAU_V;
  cur_n *= INV_TAU_I;
  potp_n *= INV_TAU_V;
  curp_n *= INV_TAU_I;

  if (s) pot_n = 0.0f;
  if (sp) potp_n = 0.0f;
  int rn = s ? 2 : rd;

  pot_out[e] = pot_n;
  cur_out[e] = cur_n;
  potp_out[e] = potp_n;
  curp_out[e] = curp_n;
  refrac_out[e] = (float)rn;
}

// ---------------------------------------------------------------------------
extern "C" void kernel_launch(void* const* d_in, const int* in_sizes, int n_in,
                              void* d_out, int out_size, void* d_ws, size_t ws_size,
                              hipStream_t stream) {
  const float* inp = (const float*)d_in[0];
  const float* W = (const float*)d_in[1];
  const float* mem_pot = (const float*)d_in[2];
  const float* mem_cur = (const float*)d_in[3];
  const float* mem_pot_p = (const float*)d_in[4];
  const float* mem_cur_p = (const float*)d_in[5];
  const float* st = (const float*)d_in[6];
  const int* refrac = (const int*)d_in[7];

  float* out = (float*)d_out;
  float* S_out = out;
  float* pot_out = out + BN;
  float* W_out = out + 2 * (size_t)BN;
  float* cur_out = W_out + NN;
  float* potp_out = cur_out + BN;
  float* curp_out = potp_out + BN;
  float* refrac_out = curp_out + BN;

  // Workspace layout (16B-aligned), ~16.6 MB total
  uint32_t* maskS = (uint32_t*)d_ws;                      // 16 KB
  uint32_t* maskSP = maskS + N;                           // 16 KB
  float* max_st = (float*)(maskSP + N);                   // 16 KB
  float* rowfac = max_st + N;                             // 16 KB
  unsigned short* S_bf = (unsigned short*)(rowfac + N);   // 256 KB
  float* partSW = (float*)(S_bf + BN);                    // NPSW*BN*4  = 8 MB
  float* partSWT = partSW + (size_t)NPSW * BN;            // NPSWT*BN*4 = 8 MB

  pass_a<<<N / 256, 256, 0, stream>>>(mem_pot, mem_pot_p, st, S_out, S_bf,
                                      maskS, maskSP, max_st, rowfac);
  pass_gemms<<<ABLK + BBLK, 256, 0, stream>>>(W, S_bf, max_st, rowfac,
                                              W_out, partSW, partSWT);
  pass_d<<<BN / 256, 256, 0, stream>>>(inp, mem_pot, mem_cur, mem_pot_p,
                                       mem_cur_p, refrac, maskS, maskSP,
                                       partSW, partSWT, pot_out, cur_out,
                                       potp_out, curp_out, refrac_out);
}

// Round 9
// 167.422 us; speedup vs baseline: 1.0833x; 1.0833x over previous
//
#include <hip/hip_runtime.h>
#include <cstdint>
#include <cstddef>

// Problem constants
constexpr int N = 4096;
constexpr int B = 32;
constexpr int BN = B * N;             // 131072
constexpr size_t NN = (size_t)N * N;  // 16777216

// GEMM pass families:
//  Family A (gemm1/SWT): 256 blocks = (it 0..31) x (jc 0..7)
//     i-panel 128 rows, K-chunk 512. LDS-free, barrier-free, K in registers.
//  Family B (gemm0/SW):  512 blocks = (jt 0..31) x (ic 0..15)
//     j-panel 128 cols, i-chunk 256 (4 subtiles of 64x128 via LDS).
constexpr int ABLK = 256;
constexpr int BBLK = 512;
constexpr int NPSWT = 8;              // partSWT copies (jc)
constexpr int NPSW = 16;              // partSW copies (ic)
constexpr int LDTB = 136;             // family B tile row stride (bf16 elems)

constexpr float ALPHA = 0.025f;
constexpr float BETA = 0.00025f;
constexpr float T_NOW = 10.0f;
constexpr float INV_EXP_TAU = 0.02f;          // 1/50
constexpr float INV_TAU_V = 0.98019867f;      // exp(-1/50)
constexpr float INV_TAU_I = 0.36787944f;      // exp(-1)

typedef __attribute__((ext_vector_type(8))) short short8;
typedef __attribute__((ext_vector_type(4))) float f32x4;

__device__ inline unsigned short f2bf(float f) {
  uint32_t u = __float_as_uint(f);
  u += 0x7FFFu + ((u >> 16) & 1u);   // RNE
  return (unsigned short)(u >> 16);
}

// W-update: u = clip(w + BETA - fac_row*exp(|mst_row-mst_col|/50), 0, 1);
// keep w where w<=0.
__device__ inline float wupd(float w, float mrow, float frow, float mcol) {
  float d = fabsf(mrow - mcol);
  float u = w + BETA - frow * __expf(d * INV_EXP_TAU);
  u = fminf(fmaxf(u, 0.0f), 1.0f);
  return (w > 0.0f) ? u : w;
}

// Barrier with LDS-only ordering (does NOT drain vmcnt: prefetch loads stay
// in flight; compiler still waits vmcnt before any load result is used).
__device__ inline void bar_lgkm() {
  asm volatile("s_waitcnt lgkmcnt(0)" ::: "memory");
  __builtin_amdgcn_sched_barrier(0);
  __builtin_amdgcn_s_barrier();
}

// ---------------------------------------------------------------------------
// Pass A: per-neuron spike masks + max_st + rowfac; writes S (f32) and S_bf.
// ---------------------------------------------------------------------------
__global__ __launch_bounds__(256) void pass_a(
    const float* __restrict__ mem_pot, const float* __restrict__ mem_pot_p,
    const float* __restrict__ st, float* __restrict__ S_out,
    unsigned short* __restrict__ S_bf,
    uint32_t* __restrict__ maskS, uint32_t* __restrict__ maskSP,
    float* __restrict__ max_st, float* __restrict__ rowfac) {
  int j = blockIdx.x * blockDim.x + threadIdx.x;
  if (j >= N) return;
  float stj = st[j];
  uint32_t ms = 0u, msp = 0u;
  float maxv = -3.0e38f;
  #pragma unroll
  for (int b = 0; b < B; ++b) {
    float p = mem_pot[b * N + j];
    float pp = mem_pot_p[b * N + j];
    bool s = (p - 1.0f) > 0.0f;
    bool sp = ((pp - 1.0f) - ALPHA) > 0.0f;
    S_out[b * N + j] = s ? 1.0f : 0.0f;
    S_bf[b * N + j] = s ? 0x3F80u : 0u;   // bf16 1.0 / 0.0
    ms |= (uint32_t)s << b;
    msp |= (uint32_t)sp << b;
    maxv = fmaxf(maxv, s ? T_NOW : stj);
  }
  maskS[j] = ms;
  maskSP[j] = msp;
  max_st[j] = maxv;
  rowfac[j] = msp ? ALPHA : 0.0f;
}

// ---------------------------------------------------------------------------
// Pass B: PURE STREAMING W-update. No LDS, no barriers, no MFMA.
// Regular (cached) stores so W_out stays LLC-resident for pass_gemm.
// 2048 blocks x 256 thr x 8 float4 each = 16.7M elements.
// ---------------------------------------------------------------------------
__global__ __launch_bounds__(256) void pass_b(
    const float* __restrict__ W, const float* __restrict__ max_st,
    const float* __restrict__ rowfac, float* __restrict__ Wout) {
  const float4* __restrict__ W4 = (const float4*)W;
  float4* __restrict__ Wo4 = (float4*)Wout;
  const float4* __restrict__ mst4 = (const float4*)max_st;
  int g0 = blockIdx.x * 256 + threadIdx.x;
  #pragma unroll
  for (int it = 0; it < 8; ++it) {
    int g = g0 + it * (2048 * 256);
    int i = g >> 10;                 // row (1024 float4 per row)
    int jc4 = g & 1023;              // float4 col
    float4 w = W4[g];
    float mi = max_st[i];
    float fi = rowfac[i];
    float4 mj = mst4[jc4];
    float4 u;
    u.x = wupd(w.x, mi, fi, mj.x);
    u.y = wupd(w.y, mi, fi, mj.y);
    u.z = wupd(w.z, mi, fi, mj.z);
    u.w = wupd(w.w, mi, fi, mj.w);
    Wo4[g] = u;
  }
}

// ---------------------------------------------------------------------------
// GEMM pass: reads W_out (f32, LLC-hot), converts to bf16 on the fly.
// MFMA layouts (verified rounds 0-8): A[m=lane&15][k=quad*8+e],
// B[k=quad*8+e][n=lane&15], C/D: col=lane&15, row=quad*4+reg.
// ---------------------------------------------------------------------------
__global__ __launch_bounds__(256, 4) void pass_gemm(
    const float* __restrict__ Wn, const unsigned short* __restrict__ S_bf,
    float* __restrict__ partSW, float* __restrict__ partSWT) {
  __shared__ __align__(16) unsigned short tileB[64 * LDTB];

  int tid = threadIdx.x;
  int wv = tid >> 6;
  int lane = tid & 63;
  int quad = lane >> 4;
  int nl = lane & 15;

  if (blockIdx.x < ABLK) {
    // ======= Family A: gemm1 (SWT) — LDS-free, barrier-free =======
    // SWT[b,i] = sum_j S[b,j] * Wn[i,j]; B-frag rows are contiguous in Wn.
    int it = blockIdx.x & 31;
    int jc = blockIdx.x >> 5;        // 0..7
    int i0 = it * 128;
    int kbase = jc * 512;

    f32x4 acc[2][2];                 // [ntile][batch-half]
    #pragma unroll
    for (int a = 0; a < 2; ++a)
      #pragma unroll
      for (int h = 0; h < 2; ++h) acc[a][h] = (f32x4){0.f, 0.f, 0.f, 0.f};

    const float* __restrict__ wr0 =
        Wn + (size_t)(i0 + wv * 32 + nl) * N;        // ntile 0 row
    const float* __restrict__ wr1 = wr0 + (size_t)16 * N;  // ntile 1 row

    #pragma unroll 2
    for (int ks = 0; ks < 16; ++ks) {
      int k = kbase + ks * 32 + quad * 8;
      short8 a0 = *(const short8*)(S_bf + (size_t)nl * N + k);
      short8 a1 = *(const short8*)(S_bf + (size_t)(nl + 16) * N + k);
      // ntile 0
      {
        float4 f0 = *(const float4*)(wr0 + k);
        float4 f1 = *(const float4*)(wr0 + k + 4);
        short8 b;
        b[0] = (short)f2bf(f0.x); b[1] = (short)f2bf(f0.y);
        b[2] = (short)f2bf(f0.z); b[3] = (short)f2bf(f0.w);
        b[4] = (short)f2bf(f1.x); b[5] = (short)f2bf(f1.y);
        b[6] = (short)f2bf(f1.z); b[7] = (short)f2bf(f1.w);
        acc[0][0] = __builtin_amdgcn_mfma_f32_16x16x32_bf16(a0, b, acc[0][0], 0, 0, 0);
        acc[0][1] = __builtin_amdgcn_mfma_f32_16x16x32_bf16(a1, b, acc[0][1], 0, 0, 0);
      }
      // ntile 1
      {
        float4 f0 = *(const float4*)(wr1 + k);
        float4 f1 = *(const float4*)(wr1 + k + 4);
        short8 b;
        b[0] = (short)f2bf(f0.x); b[1] = (short)f2bf(f0.y);
        b[2] = (short)f2bf(f0.z); b[3] = (short)f2bf(f0.w);
        b[4] = (short)f2bf(f1.x); b[5] = (short)f2bf(f1.y);
        b[6] = (short)f2bf(f1.z); b[7] = (short)f2bf(f1.w);
        acc[1][0] = __builtin_amdgcn_mfma_f32_16x16x32_bf16(a0, b, acc[1][0], 0, 0, 0);
        acc[1][1] = __builtin_amdgcn_mfma_f32_16x16x32_bf16(a1, b, acc[1][1], 0, 0, 0);
      }
    }

    // one partSWT store (K=512 accumulated)
    size_t baseA = (size_t)jc * BN;
    #pragma unroll
    for (int nt = 0; nt < 2; ++nt) {
      int ig = i0 + wv * 32 + nt * 16 + nl;
      #pragma unroll
      for (int r = 0; r < 4; ++r) {
        partSWT[baseA + (size_t)(quad * 4 + r) * N + ig] = acc[nt][0][r];
        partSWT[baseA + (size_t)(16 + quad * 4 + r) * N + ig] = acc[nt][1][r];
      }
    }
  } else {
    // ======= Family B: gemm0 (SW) — LDS tile, lgkm-only barriers =======
    int idx = blockIdx.x - ABLK;
    int jt = idx & 31;
    int ic = idx >> 5;               // 0..15
    int j0 = jt * 128;
    int ibase = ic * 256;
    int row8 = tid >> 5;             // 0..7 (stage-phase row stripe)
    int c4 = tid & 31;               // float4 column 0..31

    float4 pf[8];
    {
      const float* wb = Wn + (size_t)(ibase + row8) * N + j0 + c4 * 4;
      #pragma unroll
      for (int p = 0; p < 8; ++p)
        pf[p] = *(const float4*)(wb + (size_t)(p * 8) * N);
    }

    f32x4 accB[2][2];                // [j-ntile][batch-half]
    #pragma unroll
    for (int a = 0; a < 2; ++a)
      #pragma unroll
      for (int h = 0; h < 2; ++h) accB[a][h] = (f32x4){0.f, 0.f, 0.f, 0.f};

    #pragma unroll 1
    for (int isub = 0; isub < 4; ++isub) {
      // A-fragments for this i-window (complete during stage)
      short8 aB0[2], aB1[2];
      #pragma unroll
      for (int ks = 0; ks < 2; ++ks) {
        int kg = ibase + isub * 64 + ks * 32 + quad * 8;
        aB0[ks] = *(const short8*)(S_bf + (size_t)nl * N + kg);
        aB1[ks] = *(const short8*)(S_bf + (size_t)(nl + 16) * N + kg);
      }
      // stage: f2bf -> LDS (row-major, LDTB stride)
      #pragma unroll
      for (int p = 0; p < 8; ++p) {
        int r = p * 8 + row8;
        uint32_t d0 = (uint32_t)f2bf(pf[p].x) | ((uint32_t)f2bf(pf[p].y) << 16);
        uint32_t d1 = (uint32_t)f2bf(pf[p].z) | ((uint32_t)f2bf(pf[p].w) << 16);
        uint2 dd; dd.x = d0; dd.y = d1;
        *(uint2*)((char*)tileB + r * (LDTB * 2) + c4 * 8) = dd;
      }
      // prefetch next sub-tile (stays in flight through MFMA phase)
      if (isub + 1 < 4) {
        const float* wb =
            Wn + (size_t)(ibase + (isub + 1) * 64 + row8) * N + j0 + c4 * 4;
        #pragma unroll
        for (int p = 0; p < 8; ++p)
          pf[p] = *(const float4*)(wb + (size_t)(p * 8) * N);
      }
      bar_lgkm();                    // tile ready (vmcnt NOT drained)

      // gemm0 MFMA: wave owns j-ntiles wv*2, wv*2+1 (balanced)
      #pragma unroll
      for (int ks = 0; ks < 2; ++ks) {
        #pragma unroll
        for (int t = 0; t < 2; ++t) {
          int js = wv * 2 + t;
          short8 b;
          #pragma unroll
          for (int e = 0; e < 8; ++e)
            b[e] = (short)tileB[(ks * 32 + quad * 8 + e) * LDTB + js * 16 + nl];
          accB[t][0] =
              __builtin_amdgcn_mfma_f32_16x16x32_bf16(aB0[ks], b, accB[t][0], 0, 0, 0);
          accB[t][1] =
              __builtin_amdgcn_mfma_f32_16x16x32_bf16(aB1[ks], b, accB[t][1], 0, 0, 0);
        }
      }
      if (isub + 1 < 4) bar_lgkm();  // reads done before overwrite
    }

    // one partSW store (K=256 accumulated)
    size_t baseB = (size_t)ic * BN;
    #pragma unroll
    for (int t = 0; t < 2; ++t) {
      int jg = j0 + (wv * 2 + t) * 16 + nl;
      #pragma unroll
      for (int r = 0; r < 4; ++r) {
        partSW[baseB + (size_t)(quad * 4 + r) * N + jg] = accB[t][0][r];
        partSW[baseB + (size_t)(16 + quad * 4 + r) * N + jg] = accB[t][1][r];
      }
    }
  }
}

// ---------------------------------------------------------------------------
// Pass D: reduce partials, integrate + leak + reset + refractory.
// ---------------------------------------------------------------------------
__global__ __launch_bounds__(256) void pass_d(
    const float* __restrict__ inp, const float* __restrict__ mem_pot,
    const float* __restrict__ mem_cur, const float* __restrict__ mem_pot_p,
    const float* __restrict__ mem_cur_p, const int* __restrict__ refrac_in,
    const uint32_t* __restrict__ maskS, const uint32_t* __restrict__ maskSP,
    const float* __restrict__ partSW, const float* __restrict__ partSWT,
    float* __restrict__ pot_out, float* __restrict__ cur_out,
    float* __restrict__ potp_out, float* __restrict__ curp_out,
    float* __restrict__ refrac_out) {
  int e = blockIdx.x * 256 + threadIdx.x;
  int b = e >> 12;
  int j = e & (N - 1);

  float SW = 0.0f, SWT = 0.0f;
  #pragma unroll
  for (int c = 0; c < NPSW; ++c) SW += partSW[(size_t)c * BN + e];
  #pragma unroll
  for (int c = 0; c < NPSWT; ++c) SWT += partSWT[(size_t)c * BN + e];

  int r = refrac_in[e];
  int rd = (r > 0) ? (r - 1) : r;
  bool active = (rd == 0);
  bool s = (maskS[j] >> b) & 1u;
  bool sp = (maskSP[j] >> b) & 1u;
  float cur = mem_cur[e], pot = mem_pot[e];
  float curp = mem_cur_p[e], potp = mem_pot_p[e];

  float cur_n = active ? (inp[e] + SW + cur) : cur;
  float curp_n = active ? (SWT + curp) : curp;
  float pot_n = active ? (cur_n + pot) : pot;
  float potp_n = active ? (curp_n + potp) : potp;

  pot_n *= INV_TAU_V;
  cur_n *= INV_TAU_I;
  potp_n *= INV_TAU_V;
  curp_n *= INV_TAU_I;

  if (s) pot_n = 0.0f;
  if (sp) potp_n = 0.0f;
  int rn = s ? 2 : rd;

  pot_out[e] = pot_n;
  cur_out[e] = cur_n;
  potp_out[e] = potp_n;
  curp_out[e] = curp_n;
  refrac_out[e] = (float)rn;
}

// ---------------------------------------------------------------------------
extern "C" void kernel_launch(void* const* d_in, const int* in_sizes, int n_in,
                              void* d_out, int out_size, void* d_ws, size_t ws_size,
                              hipStream_t stream) {
  const float* inp = (const float*)d_in[0];
  const float* W = (const float*)d_in[1];
  const float* mem_pot = (const float*)d_in[2];
  const float* mem_cur = (const float*)d_in[3];
  const float* mem_pot_p = (const float*)d_in[4];
  const float* mem_cur_p = (const float*)d_in[5];
  const float* st = (const float*)d_in[6];
  const int* refrac = (const int*)d_in[7];

  float* out = (float*)d_out;
  float* S_out = out;
  float* pot_out = out + BN;
  float* W_out = out + 2 * (size_t)BN;
  float* cur_out = W_out + NN;
  float* potp_out = cur_out + BN;
  float* curp_out = potp_out + BN;
  float* refrac_out = curp_out + BN;

  // Workspace layout (16B-aligned), ~12.6 MB total
  uint32_t* maskS = (uint32_t*)d_ws;                      // 16 KB
  uint32_t* maskSP = maskS + N;                           // 16 KB
  float* max_st = (float*)(maskSP + N);                   // 16 KB
  float* rowfac = max_st + N;                             // 16 KB
  unsigned short* S_bf = (unsigned short*)(rowfac + N);   // 256 KB
  float* partSW = (float*)(S_bf + BN);                    // NPSW*BN*4  = 8 MB
  float* partSWT = partSW + (size_t)NPSW * BN;            // NPSWT*BN*4 = 4 MB

  pass_a<<<N / 256, 256, 0, stream>>>(mem_pot, mem_pot_p, st, S_out, S_bf,
                                      maskS, maskSP, max_st, rowfac);
  pass_b<<<2048, 256, 0, stream>>>(W, max_st, rowfac, W_out);
  pass_gemm<<<ABLK + BBLK, 256, 0, stream>>>(W_out, S_bf, partSW, partSWT);
  pass_d<<<BN / 256, 256, 0, stream>>>(inp, mem_pot, mem_cur, mem_pot_p,
                                       mem_cur_p, refrac, maskS, maskSP,
                                       partSW, partSWT, pot_out, cur_out,
                                       potp_out, curp_out, refrac_out);
}

// Round 10
// 167.353 us; speedup vs baseline: 1.0837x; 1.0004x over previous
//
#include <hip/hip_runtime.h>
#include <cstdint>
#include <cstddef>

// Problem constants
constexpr int N = 4096;
constexpr int B = 32;
constexpr int BN = B * N;             // 131072
constexpr size_t NN = (size_t)N * N;  // 16777216

// Two-family GEMM pass (768 blocks, R7 grid):
//  Family A (gemm1 + W_out): 256 blocks = (it 0..31) x (jc 0..7)
//     i-panel 128 rows, K-chunk 512 as 8 jsubs of 64 cols; deep prefetch.
//  Family B (gemm0):         512 blocks = (jt 0..31) x (ic 0..15)
//     j-panel 128 cols, i-chunk 256 (4 subtiles of 64x128 via LDS).
constexpr int ABLK = 256;
constexpr int BBLK = 512;
constexpr int NPSWT = 8;              // partSWT copies (jc)
constexpr int NPSW = 16;              // partSW copies (ic)
constexpr int LDTB = 136;             // family B tile row stride (bf16 elems)

constexpr float ALPHA = 0.025f;
constexpr float BETA = 0.00025f;
constexpr float T_NOW = 10.0f;
constexpr float INV_EXP_TAU = 0.02f;          // 1/50
constexpr float INV_TAU_V = 0.98019867f;      // exp(-1/50)
constexpr float INV_TAU_I = 0.36787944f;      // exp(-1)

typedef __attribute__((ext_vector_type(8))) short short8;
typedef __attribute__((ext_vector_type(4))) float f32x4;

__device__ inline unsigned short f2bf(float f) {
  uint32_t u = __float_as_uint(f);
  u += 0x7FFFu + ((u >> 16) & 1u);   // RNE
  return (unsigned short)(u >> 16);
}

// W-update: u = clip(w + BETA - fac_row*exp(|mst_row-mst_col|/50), 0, 1);
// keep w where w<=0.
__device__ inline float wupd(float w, float mrow, float frow, float mcol) {
  float d = fabsf(mrow - mcol);
  float u = w + BETA - frow * __expf(d * INV_EXP_TAU);
  u = fminf(fmaxf(u, 0.0f), 1.0f);
  return (w > 0.0f) ? u : w;
}

// Barrier with LDS-only ordering (does NOT drain vmcnt: W_out stores and
// prefetch loads stay in flight; compiler still waits vmcnt before use).
__device__ inline void bar_lgkm() {
  asm volatile("s_waitcnt lgkmcnt(0)" ::: "memory");
  __builtin_amdgcn_sched_barrier(0);
  __builtin_amdgcn_s_barrier();
  __builtin_amdgcn_sched_barrier(0);
}

// ---------------------------------------------------------------------------
// Pass A: per-neuron spike masks + max_st + rowfac; writes S (f32) and S_bf.
// ---------------------------------------------------------------------------
__global__ __launch_bounds__(256) void pass_a(
    const float* __restrict__ mem_pot, const float* __restrict__ mem_pot_p,
    const float* __restrict__ st, float* __restrict__ S_out,
    unsigned short* __restrict__ S_bf,
    uint32_t* __restrict__ maskS, uint32_t* __restrict__ maskSP,
    float* __restrict__ max_st, float* __restrict__ rowfac) {
  int j = blockIdx.x * blockDim.x + threadIdx.x;
  if (j >= N) return;
  float stj = st[j];
  uint32_t ms = 0u, msp = 0u;
  float maxv = -3.0e38f;
  #pragma unroll
  for (int b = 0; b < B; ++b) {
    float p = mem_pot[b * N + j];
    float pp = mem_pot_p[b * N + j];
    bool s = (p - 1.0f) > 0.0f;
    bool sp = ((pp - 1.0f) - ALPHA) > 0.0f;
    S_out[b * N + j] = s ? 1.0f : 0.0f;
    S_bf[b * N + j] = s ? 0x3F80u : 0u;   // bf16 1.0 / 0.0
    ms |= (uint32_t)s << b;
    msp |= (uint32_t)sp << b;
    maxv = fmaxf(maxv, s ? T_NOW : stj);
  }
  maskS[j] = ms;
  maskSP[j] = msp;
  max_st[j] = maxv;
  rowfac[j] = msp ? ALPHA : 0.0f;
}

// ---------------------------------------------------------------------------
// Two-family fused GEMM pass (one launch; block-uniform branch).
// MFMA layouts (verified rounds 0-9): A[m=lane&15][k=quad*8+e],
// B[k=quad*8+e][n=lane&15], C/D: col=lane&15, row=quad*4+reg.
// Family A LDS tile (128 rows x 64 bf16 = 128B rows): 16B-unit XOR swizzle
// unit' = unit ^ (row&7).
// ---------------------------------------------------------------------------
__global__ __launch_bounds__(256, 4) void pass_gemms(
    const float* __restrict__ W, const unsigned short* __restrict__ S_bf,
    const float* __restrict__ max_st, const float* __restrict__ rowfac,
    float* __restrict__ Wout, float* __restrict__ partSW,
    float* __restrict__ partSWT) {
  __shared__ __align__(16) char smem[19968];

  int tid = threadIdx.x;
  int wv = tid >> 6;
  int lane = tid & 63;
  int quad = lane >> 4;
  int nl = lane & 15;

  if (blockIdx.x < ABLK) {
    // =================== Family A: gemm1 (SWT) + W_out ===================
    int it = blockIdx.x & 31;
    int jc = blockIdx.x >> 5;        // 0..7
    int i0 = it * 128;
    int c4b = tid & 15;              // f4 col 0..15 (64-wide jsub)
    int rowX = tid >> 4;             // 0..15 row stripe
    float* mstIA = (float*)(smem + 16384);
    float* facIA = mstIA + 128;

    if (tid < 128) {
      mstIA[tid] = max_st[i0 + tid];
      facIA[tid] = rowfac[i0 + tid];
    }

    f32x4 acc[2][2];                 // [ntile][batch-half]
    #pragma unroll
    for (int a = 0; a < 2; ++a)
      #pragma unroll
      for (int h = 0; h < 2; ++h) acc[a][h] = (f32x4){0.f, 0.f, 0.f, 0.f};

    float4 pfA[8], pfB[8];
    int jb0 = jc * 512;
    {
      const float* wb = W + (size_t)(i0 + rowX) * N + jb0 + c4b * 4;
      #pragma unroll
      for (int p = 0; p < 8; ++p)
        pfA[p] = *(const float4*)(wb + (size_t)(p * 16) * N);
    }

    bar_lgkm();                      // mstIA/facIA visible

    auto iterA = [&](int jb, int jbn, float4 (&pfc)[8], float4 (&pfn)[8],
                     bool pre, bool last) {
      // prefetch next jsub (full phase of latency hiding)
      if (pre) {
        const float* wb = W + (size_t)(i0 + rowX) * N + jbn + c4b * 4;
        #pragma unroll
        for (int p = 0; p < 8; ++p)
          pfn[p] = *(const float4*)(wb + (size_t)(p * 16) * N);
      }
      // A-fragments for this 64-wide k-window (complete during stage)
      short8 aA0[2], aA1[2];
      #pragma unroll
      for (int ks = 0; ks < 2; ++ks) {
        int kg = jb + ks * 32 + quad * 8;
        aA0[ks] = *(const short8*)(S_bf + (size_t)nl * N + kg);
        aA1[ks] = *(const short8*)(S_bf + (size_t)(nl + 16) * N + kg);
      }
      float4 mj4 = *(const float4*)(max_st + jb + c4b * 4);
      // stage: wupd + W_out (nontemporal) + bf16 -> swizzled LDS
      #pragma unroll
      for (int p = 0; p < 8; ++p) {
        int r = p * 16 + rowX;
        float mi = mstIA[r];
        float fi = facIA[r];
        f32x4 u;
        u[0] = wupd(pfc[p].x, mi, fi, mj4.x);
        u[1] = wupd(pfc[p].y, mi, fi, mj4.y);
        u[2] = wupd(pfc[p].z, mi, fi, mj4.z);
        u[3] = wupd(pfc[p].w, mi, fi, mj4.w);
        __builtin_nontemporal_store(
            u, (f32x4*)(Wout + (size_t)(i0 + r) * N + jb + c4b * 4));
        uint32_t d0 = (uint32_t)f2bf(u[0]) | ((uint32_t)f2bf(u[1]) << 16);
        uint32_t d1 = (uint32_t)f2bf(u[2]) | ((uint32_t)f2bf(u[3]) << 16);
        uint2 dd; dd.x = d0; dd.y = d1;
        *(uint2*)(smem + r * 128 + ((((c4b >> 1) ^ (r & 7))) << 4) +
                  ((c4b & 1) << 3)) = dd;
      }
      bar_lgkm();                    // tile ready (vmcnt NOT drained)
      // gemm1 MFMA: wave owns rows wv*32..wv*32+31 (2 n-tiles of 16 i's)
      #pragma unroll
      for (int ks = 0; ks < 2; ++ks) {
        #pragma unroll
        for (int nt = 0; nt < 2; ++nt) {
          int rr = wv * 32 + nt * 16 + nl;
          short8 bfr = *(const short8*)(
              smem + rr * 128 + ((((ks * 4 + quad) ^ (rr & 7))) << 4));
          acc[nt][0] =
              __builtin_amdgcn_mfma_f32_16x16x32_bf16(aA0[ks], bfr, acc[nt][0], 0, 0, 0);
          acc[nt][1] =
              __builtin_amdgcn_mfma_f32_16x16x32_bf16(aA1[ks], bfr, acc[nt][1], 0, 0, 0);
        }
      }
      if (!last) bar_lgkm();         // reads done before overwrite
    };

    iterA(jb0 +   0, jb0 +  64, pfA, pfB, true , false);
    iterA(jb0 +  64, jb0 + 128, pfB, pfA, true , false);
    iterA(jb0 + 128, jb0 + 192, pfA, pfB, true , false);
    iterA(jb0 + 192, jb0 + 256, pfB, pfA, true , false);
    iterA(jb0 + 256, jb0 + 320, pfA, pfB, true , false);
    iterA(jb0 + 320, jb0 + 384, pfB, pfA, true , false);
    iterA(jb0 + 384, jb0 + 448, pfA, pfB, true , false);
    iterA(jb0 + 448, 0,         pfB, pfA, false, true );

    // epilogue: one partSWT store (K=512 accumulated)
    size_t baseA = (size_t)jc * BN;
    #pragma unroll
    for (int nt = 0; nt < 2; ++nt) {
      int ig = i0 + wv * 32 + nt * 16 + nl;
      #pragma unroll
      for (int r = 0; r < 4; ++r) {
        partSWT[baseA + (size_t)(quad * 4 + r) * N + ig] = acc[nt][0][r];
        partSWT[baseA + (size_t)(16 + quad * 4 + r) * N + ig] = acc[nt][1][r];
      }
    }
  } else {
    // =================== Family B: gemm0 (SW) ===================
    int idx = blockIdx.x - ABLK;
    int jt = idx & 31;
    int ic = idx >> 5;               // 0..15
    int j0 = jt * 128;
    int ibase = ic * 256;
    int row8 = tid >> 5;             // 0..7 (stage-phase row stripe)
    int c4 = tid & 31;               // float4 column 0..31
    unsigned short* tileB = (unsigned short*)smem;      // [64][LDTB]
    float* mstIB = (float*)(smem + 17408);
    float* facIB = mstIB + 256;
    float* mstJB = facIB + 256;

    mstIB[tid] = max_st[ibase + tid];
    facIB[tid] = rowfac[ibase + tid];
    if (tid < 128) mstJB[tid] = max_st[j0 + tid];

    float4 pf[8];
    {
      const float* wb = W + (size_t)(ibase + row8) * N + j0 + c4 * 4;
      #pragma unroll
      for (int p = 0; p < 8; ++p)
        pf[p] = *(const float4*)(wb + (size_t)(p * 8) * N);
    }

    f32x4 accB[2][2];                // [j-ntile][batch-half]
    #pragma unroll
    for (int a = 0; a < 2; ++a)
      #pragma unroll
      for (int h = 0; h < 2; ++h) accB[a][h] = (f32x4){0.f, 0.f, 0.f, 0.f};

    bar_lgkm();                      // mst/fac visible

    #pragma unroll 1
    for (int isub = 0; isub < 4; ++isub) {
      // A-fragments for this i-window (complete during stage)
      short8 aB0[2], aB1[2];
      #pragma unroll
      for (int ks = 0; ks < 2; ++ks) {
        int kg = ibase + isub * 64 + ks * 32 + quad * 8;
        aB0[ks] = *(const short8*)(S_bf + (size_t)nl * N + kg);
        aB1[ks] = *(const short8*)(S_bf + (size_t)(nl + 16) * N + kg);
      }
      float4 mjB = *(const float4*)(mstJB + c4 * 4);
      #pragma unroll
      for (int p = 0; p < 8; ++p) {
        int r = p * 8 + row8;
        float mi = mstIB[isub * 64 + r];
        float fi = facIB[isub * 64 + r];
        float ux = wupd(pf[p].x, mi, fi, mjB.x);
        float uy = wupd(pf[p].y, mi, fi, mjB.y);
        float uz = wupd(pf[p].z, mi, fi, mjB.z);
        float uw = wupd(pf[p].w, mi, fi, mjB.w);
        uint32_t d0 = (uint32_t)f2bf(ux) | ((uint32_t)f2bf(uy) << 16);
        uint32_t d1 = (uint32_t)f2bf(uz) | ((uint32_t)f2bf(uw) << 16);
        uint2 dd; dd.x = d0; dd.y = d1;
        *(uint2*)((char*)tileB + r * (LDTB * 2) + c4 * 8) = dd;
      }
      // prefetch next sub-tile (stays in flight through MFMA phase)
      if (isub + 1 < 4) {
        const float* wb =
            W + (size_t)(ibase + (isub + 1) * 64 + row8) * N + j0 + c4 * 4;
        #pragma unroll
        for (int p = 0; p < 8; ++p)
          pf[p] = *(const float4*)(wb + (size_t)(p * 8) * N);
      }
      bar_lgkm();                    // tile ready (vmcnt NOT drained)

      // gemm0 MFMA: wave owns j-ntiles wv*2, wv*2+1 (balanced)
      #pragma unroll
      for (int ks = 0; ks < 2; ++ks) {
        #pragma unroll
        for (int t = 0; t < 2; ++t) {
          int js = wv * 2 + t;
          short8 b;
          #pragma unroll
          for (int e = 0; e < 8; ++e)
            b[e] = (short)tileB[(ks * 32 + quad * 8 + e) * LDTB + js * 16 + nl];
          accB[t][0] =
              __builtin_amdgcn_mfma_f32_16x16x32_bf16(aB0[ks], b, accB[t][0], 0, 0, 0);
          accB[t][1] =
              __builtin_amdgcn_mfma_f32_16x16x32_bf16(aB1[ks], b, accB[t][1], 0, 0, 0);
        }
      }
      if (isub + 1 < 4) bar_lgkm();  // reads done before overwrite
    }

    // epilogue: one partSW store (K=256 accumulated)
    size_t baseB = (size_t)ic * BN;
    #pragma unroll
    for (int t = 0; t < 2; ++t) {
      int jg = j0 + (wv * 2 + t) * 16 + nl;
      #pragma unroll
      for (int r = 0; r < 4; ++r) {
        partSW[baseB + (size_t)(quad * 4 + r) * N + jg] = accB[t][0][r];
        partSW[baseB + (size_t)(16 + quad * 4 + r) * N + jg] = accB[t][1][r];
      }
    }
  }
}

// ---------------------------------------------------------------------------
// Pass D: reduce partials, integrate + leak + reset + refractory.
// ---------------------------------------------------------------------------
__global__ __launch_bounds__(256) void pass_d(
    const float* __restrict__ inp, const float* __restrict__ mem_pot,
    const float* __restrict__ mem_cur, const float* __restrict__ mem_pot_p,
    const float* __restrict__ mem_cur_p, const int* __restrict__ refrac_in,
    const uint32_t* __restrict__ maskS, const uint32_t* __restrict__ maskSP,
    const float* __restrict__ partSW, const float* __restrict__ partSWT,
    float* __restrict__ pot_out, float* __restrict__ cur_out,
    float* __restrict__ potp_out, float* __restrict__ curp_out,
    float* __restrict__ refrac_out) {
  int e = blockIdx.x * 256 + threadIdx.x;
  int b = e >> 12;
  int j = e & (N - 1);

  float SW = 0.0f, SWT = 0.0f;
  #pragma unroll
  for (int c = 0; c < NPSW; ++c) SW += partSW[(size_t)c * BN + e];
  #pragma unroll
  for (int c = 0; c < NPSWT; ++c) SWT += partSWT[(size_t)c * BN + e];

  int r = refrac_in[e];
  int rd = (r > 0) ? (r - 1) : r;
  bool active = (rd == 0);
  bool s = (maskS[j] >> b) & 1u;
  bool sp = (maskSP[j] >> b) & 1u;
  float cur = mem_cur[e], pot = mem_pot[e];
  float curp = mem_cur_p[e], potp = mem_pot_p[e];

  float cur_n = active ? (inp[e] + SW + cur) : cur;
  float curp_n = active ? (SWT + curp) : curp;
  float pot_n = active ? (cur_n + pot) : pot;
  float potp_n = active ? (curp_n + potp) : potp;

  pot_n *= INV_TAU_V;
  cur_n *= INV_TAU_I;
  potp_n *= INV_TAU_V;
  curp_n *= INV_TAU_I;

  if (s) pot_n = 0.0f;
  if (sp) potp_n = 0.0f;
  int rn = s ? 2 : rd;

  pot_out[e] = pot_n;
  cur_out[e] = cur_n;
  potp_out[e] = potp_n;
  curp_out[e] = curp_n;
  refrac_out[e] = (float)rn;
}

// ---------------------------------------------------------------------------
extern "C" void kernel_launch(void* const* d_in, const int* in_sizes, int n_in,
                              void* d_out, int out_size, void* d_ws, size_t ws_size,
                              hipStream_t stream) {
  const float* inp = (const float*)d_in[0];
  const float* W = (const float*)d_in[1];
  const float* mem_pot = (const float*)d_in[2];
  const float* mem_cur = (const float*)d_in[3];
  const float* mem_pot_p = (const float*)d_in[4];
  const float* mem_cur_p = (const float*)d_in[5];
  const float* st = (const float*)d_in[6];
  const int* refrac = (const int*)d_in[7];

  float* out = (float*)d_out;
  float* S_out = out;
  float* pot_out = out + BN;
  float* W_out = out + 2 * (size_t)BN;
  float* cur_out = W_out + NN;
  float* potp_out = cur_out + BN;
  float* curp_out = potp_out + BN;
  float* refrac_out = curp_out + BN;

  // Workspace layout (16B-aligned), ~12.6 MB total
  uint32_t* maskS = (uint32_t*)d_ws;                      // 16 KB
  uint32_t* maskSP = maskS + N;                           // 16 KB
  float* max_st = (float*)(maskSP + N);                   // 16 KB
  float* rowfac = max_st + N;                             // 16 KB
  unsigned short* S_bf = (unsigned short*)(rowfac + N);   // 256 KB
  float* partSW = (float*)(S_bf + BN);                    // NPSW*BN*4  = 8 MB
  float* partSWT = partSW + (size_t)NPSW * BN;            // NPSWT*BN*4 = 4 MB

  pass_a<<<N / 256, 256, 0, stream>>>(mem_pot, mem_pot_p, st, S_out, S_bf,
                                      maskS, maskSP, max_st, rowfac);
  pass_gemms<<<ABLK + BBLK, 256, 0, stream>>>(W, S_bf, max_st, rowfac,
                                              W_out, partSW, partSWT);
  pass_d<<<BN / 256, 256, 0, stream>>>(inp, mem_pot, mem_cur, mem_pot_p,
                                       mem_cur_p, refrac, maskS, maskSP,
                                       partSW, partSWT, pot_out, cur_out,
                                       potp_out, curp_out, refrac_out);
}

// Round 11
// 155.477 us; speedup vs baseline: 1.1665x; 1.0764x over previous
//
#include <hip/hip_runtime.h>
#include <cstdint>
#include <cstddef>

// Problem constants
constexpr int N = 4096;
constexpr int B = 32;
constexpr int BN = B * N;             // 131072
constexpr size_t NN = (size_t)N * N;  // 16777216

// Two-family GEMM pass (768 blocks, R7 grid):
//  Family A (gemm1 + W_out): 256 blocks = (it 0..31) x (jc 0..7)
//     i-panel 128 rows, j-chunk 512 (4 subtiles of 128). K accum = 512.
//  Family B (gemm0):         512 blocks = (jt 0..31) x (ic 0..15)
//     j-panel 128 cols, i-chunk 256 (4 subtiles of 64x128 via LDS).
constexpr int ABLK = 256;
constexpr int BBLK = 512;
constexpr int LDTB = 136;             // family B tile row stride (bf16 elems)

constexpr float ALPHA = 0.025f;
constexpr float BETA = 0.00025f;
constexpr float T_NOW = 10.0f;
constexpr float INV_EXP_TAU = 0.02f;          // 1/50
constexpr float INV_TAU_V = 0.98019867f;      // exp(-1/50)
constexpr float INV_TAU_I = 0.36787944f;      // exp(-1)

typedef __attribute__((ext_vector_type(8))) short short8;
typedef __attribute__((ext_vector_type(4))) float f32x4;

__device__ inline unsigned short f2bf(float f) {
  uint32_t u = __float_as_uint(f);
  u += 0x7FFFu + ((u >> 16) & 1u);   // RNE
  return (unsigned short)(u >> 16);
}

// W-update: u = clip(w + BETA - fac_row*exp(|mst_row-mst_col|/50), 0, 1);
// keep w where w<=0.
__device__ inline float wupd(float w, float mrow, float frow, float mcol) {
  float d = fabsf(mrow - mcol);
  float u = w + BETA - frow * __expf(d * INV_EXP_TAU);
  u = fminf(fmaxf(u, 0.0f), 1.0f);
  return (w > 0.0f) ? u : w;
}

// ---------------------------------------------------------------------------
// Pass A: per-neuron spike masks + max_st + rowfac; writes S (f32) and S_bf.
// Also zeroes the SW/SWT atomic accumulators (R1 pattern).
// ---------------------------------------------------------------------------
__global__ __launch_bounds__(256) void pass_a(
    const float* __restrict__ mem_pot, const float* __restrict__ mem_pot_p,
    const float* __restrict__ st, float* __restrict__ S_out,
    unsigned short* __restrict__ S_bf,
    uint32_t* __restrict__ maskS, uint32_t* __restrict__ maskSP,
    float* __restrict__ max_st, float* __restrict__ rowfac,
    float4* __restrict__ zero_region /* SW||SWT: 2*BN floats = 65536 f4 */) {
  int j = blockIdx.x * blockDim.x + threadIdx.x;
  if (j >= N) return;

  // zero SW/SWT accumulators (atomicAdd targets for pass_gemms)
  float4 z = {0.0f, 0.0f, 0.0f, 0.0f};
  #pragma unroll
  for (int k = 0; k < 16; ++k) zero_region[j + k * 4096] = z;

  float stj = st[j];
  uint32_t ms = 0u, msp = 0u;
  float maxv = -3.0e38f;
  #pragma unroll
  for (int b = 0; b < B; ++b) {
    float p = mem_pot[b * N + j];
    float pp = mem_pot_p[b * N + j];
    bool s = (p - 1.0f) > 0.0f;
    bool sp = ((pp - 1.0f) - ALPHA) > 0.0f;
    S_out[b * N + j] = s ? 1.0f : 0.0f;
    S_bf[b * N + j] = s ? 0x3F80u : 0u;   // bf16 1.0 / 0.0
    ms |= (uint32_t)s << b;
    msp |= (uint32_t)sp << b;
    maxv = fmaxf(maxv, s ? T_NOW : stj);
  }
  maskS[j] = ms;
  maskSP[j] = msp;
  max_st[j] = maxv;
  rowfac[j] = msp ? ALPHA : 0.0f;
}

// ---------------------------------------------------------------------------
// Two-family fused GEMM pass (one launch; block-uniform branch). R7 structure
// verbatim; epilogues are atomicAdd into L2-resident SW/SWT (0.5 MB each).
// MFMA layouts (verified rounds 0-10): A[m=lane&15][k=quad*8+e],
// B[k=quad*8+e][n=lane&15], C/D: col=lane&15, row=quad*4+reg.
// Family A LDS tile uses 16B-unit XOR swizzle: unit' = unit ^ (row&7).
// ---------------------------------------------------------------------------
__global__ __launch_bounds__(256, 3) void pass_gemms(
    const float* __restrict__ W, const unsigned short* __restrict__ S_bf,
    const float* __restrict__ max_st, const float* __restrict__ rowfac,
    float* __restrict__ Wout, float* __restrict__ SW,
    float* __restrict__ SWT) {
  __shared__ __align__(16) char smem[33792];

  int tid = threadIdx.x;
  int wv = tid >> 6;
  int lane = tid & 63;
  int quad = lane >> 4;
  int nl = lane & 15;
  int row8 = tid >> 5;               // 0..7 (stage-phase row stripe)
  int c4 = tid & 31;                 // float4 column 0..31

  if (blockIdx.x < ABLK) {
    // =================== Family A: gemm1 (SWT) + W_out ===================
    int it = blockIdx.x & 31;
    int jc = blockIdx.x >> 5;        // 0..7
    int i0 = it * 128;
    float* mstIA = (float*)(smem + 32768);
    float* facIA = mstIA + 128;

    if (tid < 128) {
      mstIA[tid] = max_st[i0 + tid];
      facIA[tid] = rowfac[i0 + tid];
    }

    f32x4 acc[2][2];                 // [ntile][batch-half]
    #pragma unroll
    for (int a = 0; a < 2; ++a)
      #pragma unroll
      for (int h = 0; h < 2; ++h) acc[a][h] = (f32x4){0.f, 0.f, 0.f, 0.f};

    __syncthreads();                 // mstIA/facIA ready

    #pragma unroll 1
    for (int jsub = 0; jsub < 4; ++jsub) {
      int jb = jc * 512 + jsub * 128;
      // load 128x128 W sub-panel: 16 float4 per thread, rows p*8+row8
      float4 pf[16];
      const float* wb = W + (size_t)(i0 + row8) * N + jb + c4 * 4;
      #pragma unroll
      for (int p = 0; p < 16; ++p)
        pf[p] = *(const float4*)(wb + (size_t)(p * 8) * N);
      // A-fragments for this j-window (issued early; complete during stage)
      short8 aA0[4], aA1[4];
      #pragma unroll
      for (int ks = 0; ks < 4; ++ks) {
        int kg = jb + ks * 32 + quad * 8;
        aA0[ks] = *(const short8*)(S_bf + (size_t)nl * N + kg);
        aA1[ks] = *(const short8*)(S_bf + (size_t)(nl + 16) * N + kg);
      }
      float4 mj4 = *(const float4*)(max_st + jb + c4 * 4);

      #pragma unroll
      for (int p = 0; p < 16; ++p) {
        int r = p * 8 + row8;
        float mi = mstIA[r];
        float fi = facIA[r];
        f32x4 u;
        u[0] = wupd(pf[p].x, mi, fi, mj4.x);
        u[1] = wupd(pf[p].y, mi, fi, mj4.y);
        u[2] = wupd(pf[p].z, mi, fi, mj4.z);
        u[3] = wupd(pf[p].w, mi, fi, mj4.w);
        __builtin_nontemporal_store(
            u, (f32x4*)(Wout + (size_t)(i0 + r) * N + jb + c4 * 4));
        uint32_t d0 = (uint32_t)f2bf(u[0]) | ((uint32_t)f2bf(u[1]) << 16);
        uint32_t d1 = (uint32_t)f2bf(u[2]) | ((uint32_t)f2bf(u[3]) << 16);
        uint2 dd; dd.x = d0; dd.y = d1;
        // swizzled write: unit (c4>>1) ^ (r&7); 8B-half select by c4&1
        *(uint2*)(smem + r * 256 + ((((c4 >> 1) ^ (r & 7))) << 4) +
                  ((c4 & 1) << 3)) = dd;
      }
      __syncthreads();               // tile ready

      // gemm1 MFMA: wave owns rows wv*32..wv*32+31 (2 n-tiles of 16 i's)
      #pragma unroll
      for (int ks = 0; ks < 4; ++ks) {
        #pragma unroll
        for (int nt = 0; nt < 2; ++nt) {
          int rr = wv * 32 + nt * 16 + nl;       // tile row (= i local)
          short8 bfr = *(const short8*)(
              smem + rr * 256 + ((((ks * 4 + quad) ^ (rr & 7))) << 4));
          acc[nt][0] =
              __builtin_amdgcn_mfma_f32_16x16x32_bf16(aA0[ks], bfr, acc[nt][0], 0, 0, 0);
          acc[nt][1] =
              __builtin_amdgcn_mfma_f32_16x16x32_bf16(aA1[ks], bfr, acc[nt][1], 0, 0, 0);
        }
      }
      if (jsub < 3) __syncthreads(); // reads done before overwrite
    }

    // epilogue: atomic-accumulate SWT (K=512 per block; 8 jc-copies merge)
    #pragma unroll
    for (int nt = 0; nt < 2; ++nt) {
      int ig = i0 + wv * 32 + nt * 16 + nl;
      #pragma unroll
      for (int r = 0; r < 4; ++r) {
        atomicAdd(SWT + (size_t)(quad * 4 + r) * N + ig, acc[nt][0][r]);
        atomicAdd(SWT + (size_t)(16 + quad * 4 + r) * N + ig, acc[nt][1][r]);
      }
    }
  } else {
    // =================== Family B: gemm0 (SW) ===================
    int idx = blockIdx.x - ABLK;
    int jt = idx & 31;
    int ic = idx >> 5;               // 0..15
    int j0 = jt * 128;
    int ibase = ic * 256;
    unsigned short* tileB = (unsigned short*)smem;      // [64][LDTB]
    float* mstIB = (float*)(smem + 17408);
    float* facIB = mstIB + 256;
    float* mstJB = facIB + 256;

    mstIB[tid] = max_st[ibase + tid];
    facIB[tid] = rowfac[ibase + tid];
    if (tid < 128) mstJB[tid] = max_st[j0 + tid];

    float4 pf[8];
    {
      const float* wb = W + (size_t)(ibase + row8) * N + j0 + c4 * 4;
      #pragma unroll
      for (int p = 0; p < 8; ++p)
        pf[p] = *(const float4*)(wb + (size_t)(p * 8) * N);
    }

    f32x4 accB[2][2];                // [j-ntile][batch-half]
    #pragma unroll
    for (int a = 0; a < 2; ++a)
      #pragma unroll
      for (int h = 0; h < 2; ++h) accB[a][h] = (f32x4){0.f, 0.f, 0.f, 0.f};

    __syncthreads();                 // mst/fac visible

    #pragma unroll 1
    for (int isub = 0; isub < 4; ++isub) {
      // A-fragments for this i-window (complete during stage)
      short8 aB0[2], aB1[2];
      #pragma unroll
      for (int ks = 0; ks < 2; ++ks) {
        int kg = ibase + isub * 64 + ks * 32 + quad * 8;
        aB0[ks] = *(const short8*)(S_bf + (size_t)nl * N + kg);
        aB1[ks] = *(const short8*)(S_bf + (size_t)(nl + 16) * N + kg);
      }
      float4 mjB = *(const float4*)(mstJB + c4 * 4);
      #pragma unroll
      for (int p = 0; p < 8; ++p) {
        int r = p * 8 + row8;
        float mi = mstIB[isub * 64 + r];
        float fi = facIB[isub * 64 + r];
        float ux = wupd(pf[p].x, mi, fi, mjB.x);
        float uy = wupd(pf[p].y, mi, fi, mjB.y);
        float uz = wupd(pf[p].z, mi, fi, mjB.z);
        float uw = wupd(pf[p].w, mi, fi, mjB.w);
        uint32_t d0 = (uint32_t)f2bf(ux) | ((uint32_t)f2bf(uy) << 16);
        uint32_t d1 = (uint32_t)f2bf(uz) | ((uint32_t)f2bf(uw) << 16);
        uint2 dd; dd.x = d0; dd.y = d1;
        *(uint2*)((char*)tileB + r * (LDTB * 2) + c4 * 8) = dd;
      }
      // prefetch next sub-tile (in flight through MFMA phase)
      if (isub + 1 < 4) {
        const float* wb =
            W + (size_t)(ibase + (isub + 1) * 64 + row8) * N + j0 + c4 * 4;
        #pragma unroll
        for (int p = 0; p < 8; ++p)
          pf[p] = *(const float4*)(wb + (size_t)(p * 8) * N);
      }
      __syncthreads();               // tile ready

      // gemm0 MFMA: wave owns j-ntiles wv*2, wv*2+1 (balanced)
      #pragma unroll
      for (int ks = 0; ks < 2; ++ks) {
        #pragma unroll
        for (int t = 0; t < 2; ++t) {
          int js = wv * 2 + t;
          short8 b;
          #pragma unroll
          for (int e = 0; e < 8; ++e)
            b[e] = (short)tileB[(ks * 32 + quad * 8 + e) * LDTB + js * 16 + nl];
          accB[t][0] =
              __builtin_amdgcn_mfma_f32_16x16x32_bf16(aB0[ks], b, accB[t][0], 0, 0, 0);
          accB[t][1] =
              __builtin_amdgcn_mfma_f32_16x16x32_bf16(aB1[ks], b, accB[t][1], 0, 0, 0);
        }
      }
      if (isub + 1 < 4) __syncthreads();
    }

    // epilogue: atomic-accumulate SW (K=256 per block; 16 ic-copies merge)
    #pragma unroll
    for (int t = 0; t < 2; ++t) {
      int jg = j0 + (wv * 2 + t) * 16 + nl;
      #pragma unroll
      for (int r = 0; r < 4; ++r) {
        atomicAdd(SW + (size_t)(quad * 4 + r) * N + jg, accB[t][0][r]);
        atomicAdd(SW + (size_t)(16 + quad * 4 + r) * N + jg, accB[t][1][r]);
      }
    }
  }
}

// ---------------------------------------------------------------------------
// Pass D: integrate + leak + reset + refractory (SW/SWT direct reads).
// ---------------------------------------------------------------------------
__global__ __launch_bounds__(256) void pass_d(
    const float* __restrict__ inp, const float* __restrict__ mem_pot,
    const float* __restrict__ mem_cur, const float* __restrict__ mem_pot_p,
    const float* __restrict__ mem_cur_p, const int* __restrict__ refrac_in,
    const uint32_t* __restrict__ maskS, const uint32_t* __restrict__ maskSP,
    const float* __restrict__ SWbuf, const float* __restrict__ SWTbuf,
    float* __restrict__ pot_out, float* __restrict__ cur_out,
    float* __restrict__ potp_out, float* __restrict__ curp_out,
    float* __restrict__ refrac_out) {
  int e = blockIdx.x * 256 + threadIdx.x;
  int b = e >> 12;
  int j = e & (N - 1);

  float SW = SWbuf[e];
  float SWT = SWTbuf[e];

  int r = refrac_in[e];
  int rd = (r > 0) ? (r - 1) : r;
  bool active = (rd == 0);
  bool s = (maskS[j] >> b) & 1u;
  bool sp = (maskSP[j] >> b) & 1u;
  float cur = mem_cur[e], pot = mem_pot[e];
  float curp = mem_cur_p[e], potp = mem_pot_p[e];

  float cur_n = active ? (inp[e] + SW + cur) : cur;
  float curp_n = active ? (SWT + curp) : curp;
  float pot_n = active ? (cur_n + pot) : pot;
  float potp_n = active ? (curp_n + potp) : potp;

  pot_n *= INV_TAU_V;
  cur_n *= INV_TAU_I;
  potp_n *= INV_TAU_V;
  curp_n *= INV_TAU_I;

  if (s) pot_n = 0.0f;
  if (sp) potp_n = 0.0f;
  int rn = s ? 2 : rd;

  pot_out[e] = pot_n;
  cur_out[e] = cur_n;
  potp_out[e] = potp_n;
  curp_out[e] = curp_n;
  refrac_out[e] = (float)rn;
}

// ---------------------------------------------------------------------------
extern "C" void kernel_launch(void* const* d_in, const int* in_sizes, int n_in,
                              void* d_out, int out_size, void* d_ws, size_t ws_size,
                              hipStream_t stream) {
  const float* inp = (const float*)d_in[0];
  const float* W = (const float*)d_in[1];
  const float* mem_pot = (const float*)d_in[2];
  const float* mem_cur = (const float*)d_in[3];
  const float* mem_pot_p = (const float*)d_in[4];
  const float* mem_cur_p = (const float*)d_in[5];
  const float* st = (const float*)d_in[6];
  const int* refrac = (const int*)d_in[7];

  float* out = (float*)d_out;
  float* S_out = out;
  float* pot_out = out + BN;
  float* W_out = out + 2 * (size_t)BN;
  float* cur_out = W_out + NN;
  float* potp_out = cur_out + BN;
  float* curp_out = potp_out + BN;
  float* refrac_out = curp_out + BN;

  // Workspace layout (16B-aligned), ~1.3 MB total
  uint32_t* maskS = (uint32_t*)d_ws;                      // 16 KB
  uint32_t* maskSP = maskS + N;                           // 16 KB
  float* max_st = (float*)(maskSP + N);                   // 16 KB
  float* rowfac = max_st + N;                             // 16 KB
  unsigned short* S_bf = (unsigned short*)(rowfac + N);   // 256 KB
  float* SW = (float*)(S_bf + BN);                        // 512 KB
  float* SWT = SW + BN;                                   // 512 KB (contiguous)

  pass_a<<<N / 256, 256, 0, stream>>>(mem_pot, mem_pot_p, st, S_out, S_bf,
                                      maskS, maskSP, max_st, rowfac,
                                      (float4*)SW);
  pass_gemms<<<ABLK + BBLK, 256, 0, stream>>>(W, S_bf, max_st, rowfac,
                                              W_out, SW, SWT);
  pass_d<<<BN / 256, 256, 0, stream>>>(inp, mem_pot, mem_cur, mem_pot_p,
                                       mem_cur_p, refrac, maskS, maskSP,
                                       SW, SWT, pot_out, cur_out,
                                       potp_out, curp_out, refrac_out);
}